// Round 7
// baseline (678.095 us; speedup 1.0000x reference)
//
#include <hip/hip_runtime.h>
#include <hip/hip_bf16.h>

#define BATCH   8192
#define IN_SZ   1024
#define HSZ     2048
#define GG      1024
#define KTOT    2048

typedef __hip_bfloat16 bf16;
typedef __attribute__((ext_vector_type(8))) short  short8;
typedef __attribute__((ext_vector_type(4))) short  short4e;
typedef __attribute__((ext_vector_type(4))) float  floatx4;

typedef __attribute__((address_space(1))) const void gvoid_t;
typedef __attribute__((address_space(3))) void       lvoid_t;

__device__ __forceinline__ void async_ld16(void* lds, const void* g) {
  __builtin_amdgcn_global_load_lds((gvoid_t*)g, (lvoid_t*)lds, 16, 0, 0);
}

// ---------------- fused prep: x->bf16, h2->bf16 float, 4 weight transposes --
__global__ void prep_all(const float* __restrict__ x, bf16* __restrict__ xb,
                         const int* __restrict__ hidden, bf16* __restrict__ hf,
                         float* accp,
                         const float* __restrict__ W_zr1, const float* __restrict__ W_g1,
                         const float* __restrict__ W_zr2, const float* __restrict__ W_g2,
                         bf16* __restrict__ wt_zr1, bf16* __restrict__ wt_g1,
                         bf16* __restrict__ wt_zr2, bf16* __restrict__ wt_g2) {
  int b = blockIdx.x;
  int t = threadIdx.x;
  if (b < 3072) {
    const float* W; bf16* Wt; int N; int tb = b;
    if (tb < 1024)      { W = W_zr1; Wt = wt_zr1; N = 2048; }
    else if (tb < 1536) { W = W_g1;  Wt = wt_g1;  N = 1024; tb -= 1024; }
    else if (tb < 2560) { W = W_zr2; Wt = wt_zr2; N = 2048; tb -= 1536; }
    else                { W = W_g2;  Wt = wt_g2;  N = 1024; tb -= 2560; }
    int ntn = N >> 6;
    int k0 = (tb / ntn) * 64, n0 = (tb % ntn) * 64;
    __shared__ float tile[64][65];
    int kk = t >> 4, nn = (t & 15) * 4;
#pragma unroll
    for (int s = 0; s < 4; ++s) {
      int row = kk + s * 16;
      float4 v = *(const float4*)&W[(size_t)(k0 + row) * N + n0 + nn];
      tile[row][nn + 0] = v.x; tile[row][nn + 1] = v.y;
      tile[row][nn + 2] = v.z; tile[row][nn + 3] = v.w;
    }
    __syncthreads();
    int k8 = (t & 7) * 8;
#pragma unroll
    for (int s = 0; s < 2; ++s) {
      int nl = (t >> 3) + s * 32;
      bf16 vals[8];
#pragma unroll
      for (int u = 0; u < 8; ++u) vals[u] = __float2bfloat16(tile[k8 + u][nl]);
      *(short8*)&Wt[(size_t)(n0 + nl) * KTOT + k0 + k8] = *(short8*)vals;
    }
  } else {
    int idx = (b - 3072) * 256 + t;
    int i = idx * 4;
    float4 xv = *(const float4*)(x + i);
    xb[i + 0] = __float2bfloat16(xv.x);
    xb[i + 1] = __float2bfloat16(xv.y);
    xb[i + 2] = __float2bfloat16(xv.z);
    xb[i + 3] = __float2bfloat16(xv.w);
    int m = i >> 10, j = i & 1023;
    int4 hv = *(const int4*)(hidden + m * HSZ + GG + j);
    const float sc = 1.0f / 8388608.0f;   // 2^-23
    hf[i + 0] = __float2bfloat16((float)hv.x * sc);
    hf[i + 1] = __float2bfloat16((float)hv.y * sc);
    hf[i + 2] = __float2bfloat16((float)hv.z * sc);
    hf[i + 3] = __float2bfloat16((float)hv.w * sc);
    if (idx == 0) *accp = 0.0f;
  }
}

// =============================================================================
// 8-phase mainloop, v2: single-read fragments + reads issued ONE PHASE AHEAD
// of their consuming MFMA, counted lgkmcnt (never 0 mid-loop except hazard
// drains), one stage-group per phase, uniform counted vmcnt gates before the
// end-barrier. LDS chunk XOR-swizzle unchanged (pre-swizzled global source,
// linear LDS dest, swizzled ds_read offset).
// v4 fix: __launch_bounds__(512, 1). hipcc's 2nd launch_bounds arg is CUDA
// min-BLOCKS/CU semantics: (512,2) meant 2 blocks x 8 waves = 4 waves/EU ->
// 128-VGPR cap -> the ~240-VGPR ping-pong working set spilled to scratch
// (r3/r4: VGPR pinned 128, FETCH +40MB, WRITE +25MB, MfmaUtil 16%). With
// min 1 block/CU (LDS forces 1 anyway): 2 waves/EU -> 256-VGPR budget.
// =============================================================================

#define BAR()        asm volatile("s_barrier" ::: "memory")
#define WAIT_VM(n)   asm volatile("s_waitcnt vmcnt(" #n ")" ::: "memory")
#define WAIT_LG(n)   asm volatile("s_waitcnt lgkmcnt(" #n ")" ::: "memory")
#define SCHED0       __builtin_amdgcn_sched_barrier(0)
#define PRIO1        __builtin_amdgcn_s_setprio(1)
#define PRIO0        __builtin_amdgcn_s_setprio(0)

// ---------------- zr geometry: BM=256 BN=256 BK=64, waves 2M x 4N ----------
#define ZR_SA(buf, qm, tk) { const int _kt = (tk) * 64; const bf16* _p; int _kl; \
  if (_kt < IN_SZ) { _p = A0g; _kl = _kt; } else { _p = A1g; _kl = _kt - IN_SZ; } \
  async_ld16(As + (buf)*16384 + (qm)*4096 + w*512 + lnoff,        _p + a_sro[qm][0] + _kl + gch8); \
  async_ld16(As + (buf)*16384 + 8192 + (qm)*4096 + w*512 + lnoff, _p + a_sro[qm][1] + _kl + gch8); }

#define ZR_SB(buf, qn, tk) { const int _k = (tk) * 64 + gch8; \
  async_ld16(Bs + (buf)*16384 + ((w>>2)*64 + (qn)*32 + (w&3)*8)*64 + lnoff,       Btg + b_sro[qn][0] + _k); \
  async_ld16(Bs + (buf)*16384 + (128 + (w>>2)*64 + (qn)*32 + (w&3)*8)*64 + lnoff, Btg + b_sro[qn][1] + _k); }

#define ZR_RDA(dst, buf, qm) { _Pragma("unroll") for (int ii = 0; ii < 4; ++ii) { \
  const bf16* _ap = As + (buf)*16384 + (wm*128 + (qm)*64 + ii*16 + r16)*64; \
  dst[ii][0] = *(const short8*)(const void*)(_ap + pcq0); \
  dst[ii][1] = *(const short8*)(const void*)(_ap + pcq1); } }

#define ZR_RDB(dst, buf, qn) { _Pragma("unroll") for (int jj = 0; jj < 2; ++jj) { \
  const bf16* _bp = Bs + (buf)*16384 + (wn*64 + (qn)*32 + jj*16 + r16)*64; \
  dst[jj][0] = *(const short8*)(const void*)(_bp + pcq0); \
  dst[jj][1] = *(const short8*)(const void*)(_bp + pcq1); } }

#define ZR_MF(qm, qn, AF, BF) { _Pragma("unroll") for (int ii = 0; ii < 4; ++ii) \
  _Pragma("unroll") for (int jj = 0; jj < 2; ++jj) { \
    floatx4& _c = acc[(qm)*4 + ii][(qn)*2 + jj]; \
    _c = __builtin_amdgcn_mfma_f32_16x16x32_bf16(AF[ii][0], BF[jj][0], _c, 0, 0, 0); \
    _c = __builtin_amdgcn_mfma_f32_16x16x32_bf16(AF[ii][1], BF[jj][1], _c, 0, 0, 0); } }

__device__ __forceinline__ void mainloop_zr(const bf16* __restrict__ A0g,
                                            const bf16* __restrict__ A1g,
                                            const bf16* __restrict__ Btg,
                                            bf16* As, bf16* Bs,
                                            int m0, int n0, floatx4 (&acc)[8][4]) {
  const int t = threadIdx.x, lane = t & 63, w = t >> 6;
  const int l3 = lane >> 3;
  const int gch8 = (((lane & 7) ^ l3) << 3);
  const int lnoff = lane << 3;
  const int wm = w & 1, wn = w >> 1;
  const int q = lane >> 4, r16 = lane & 15;
  const int pcq0 = ((q) ^ (r16 & 7)) << 3;
  const int pcq1 = ((4 + q) ^ (r16 & 7)) << 3;

  int a_sro[2][2], b_sro[2][2];
#pragma unroll
  for (int qm = 0; qm < 2; ++qm)
#pragma unroll
    for (int h = 0; h < 2; ++h)
      a_sro[qm][h] = (m0 + h*128 + qm*64 + w*8 + l3) * IN_SZ;
#pragma unroll
  for (int qn = 0; qn < 2; ++qn)
#pragma unroll
    for (int h = 0; h < 2; ++h)
      b_sro[qn][h] = (n0 + h*128 + (w>>2)*64 + qn*32 + (w&3)*8 + l3) * KTOT;

  short8 afA[4][2], afB[4][2], bfrA[2][2], bfrB[2][2];

  // prologue: stage t0->buf0, t1->buf1 in steady-state group order
  ZR_SA(0,0,0); ZR_SB(0,0,0); ZR_SB(0,1,0); ZR_SA(0,1,0);
  ZR_SA(1,0,1); ZR_SB(1,0,1); ZR_SB(1,1,1); ZR_SA(1,1,1);
  WAIT_VM(10);               // groups A0q0,B0q0,B0q1 landed
  BAR();
  ZR_RDA(afA, 0, 0);         // af(qm0, t0)
  ZR_RDB(bfrA, 0, 0);        // bfr(qn0, t0)
  WAIT_LG(0);
  BAR();

#pragma unroll 1
  for (int it = 0; it < KTOT / 128; ++it) {
    const int tn0 = (2*it + 2 < KTOT/64) ? (2*it + 2) : (KTOT/64 - 1);
    const int tn1 = (2*it + 3 < KTOT/64) ? (2*it + 3) : (KTOT/64 - 1);
    // ph1: MFMA(tE,q0,n0); read bfr(n1,tE); stage A0q0<-tn0
    ZR_RDB(bfrB,0,1); ZR_SA(0,0,tn0); BAR(); WAIT_LG(4);  SCHED0; PRIO1; ZR_MF(0,0,afA,bfrA); PRIO0; WAIT_VM(10); BAR();
    // ph2: MFMA(tE,q0,n1); read af(m1,tE); stage B0q0
    ZR_RDA(afB,0,1);  ZR_SB(0,0,tn0); BAR(); WAIT_LG(8);  SCHED0; PRIO1; ZR_MF(0,1,afA,bfrB); PRIO0; WAIT_VM(10); BAR();
    // ph3: MFMA(tE,q1,n0); read af(m0,tO)<-buf1; stage B0q1
    ZR_RDA(afA,1,0);  ZR_SB(0,1,tn0); BAR(); WAIT_LG(8);  SCHED0; PRIO1; ZR_MF(1,0,afB,bfrA); PRIO0; WAIT_VM(10); BAR();
    // ph4: MFMA(tE,q1,n1); read bfr(n0,tO); stage A0q1   [lgkm4 = hazard drain of ph3]
    ZR_RDB(bfrA,1,0); ZR_SA(0,1,tn0); BAR(); WAIT_LG(4);  SCHED0; PRIO1; ZR_MF(1,1,afB,bfrB); PRIO0; WAIT_VM(10); BAR();
    // ph5: MFMA(tO,q0,n0); read bfr(n1,tO); stage A1q0<-tn1
    ZR_RDB(bfrB,1,1); ZR_SA(1,0,tn1); BAR(); WAIT_LG(4);  SCHED0; PRIO1; ZR_MF(0,0,afA,bfrA); PRIO0; WAIT_VM(10); BAR();
    // ph6: MFMA(tO,q0,n1); read af(m1,tO); stage B1q0
    ZR_RDA(afB,1,1);  ZR_SB(1,0,tn1); BAR(); WAIT_LG(8);  SCHED0; PRIO1; ZR_MF(0,1,afA,bfrB); PRIO0; WAIT_VM(10); BAR();
    // ph7: MFMA(tO,q1,n0); read af(m0,tE+2)<-buf0; stage B1q1
    ZR_RDA(afA,0,0);  ZR_SB(1,1,tn1); BAR(); WAIT_LG(8);  SCHED0; PRIO1; ZR_MF(1,0,afB,bfrA); PRIO0; WAIT_VM(10); BAR();
    // ph8: MFMA(tO,q1,n1); read bfr(n0,tE+2); stage A1q1 [lgkm4 = hazard drain of ph7]
    ZR_RDB(bfrA,0,0); ZR_SA(1,1,tn1); BAR(); WAIT_LG(4);  SCHED0; PRIO1; ZR_MF(1,1,afB,bfrB); PRIO0; WAIT_VM(10); BAR();
  }
  asm volatile("s_waitcnt vmcnt(0)" ::: "memory");
  __syncthreads();
}

// ---------------- g geometry: BM=256 BN=128 BK=64, waves 4M x 2N -----------
// A stage groups identical to zr. B staged as ONE group (2 calls, rows 0-127).
// Wave mw covers rows (mw&1)*128 + (mw>>1)*32 + qm*64 + i*16 (i<2)  [subset of
// stage-group qm]; wave nw covers cols nw*64 + qn*32 + j*16 (j<2).
#define G_SB(buf, tk) { const int _k = (tk) * 64 + gch8; \
  async_ld16(Bs + (buf)*8192 + w*512 + lnoff,        Btg + b_srg[0] + _k); \
  async_ld16(Bs + (buf)*8192 + 4096 + w*512 + lnoff, Btg + b_srg[1] + _k); }

#define G_RDA(dst, buf, qm) { _Pragma("unroll") for (int ii = 0; ii < 2; ++ii) { \
  const bf16* _ap = As + (buf)*16384 + (mwb + (qm)*64 + ii*16 + r16)*64; \
  dst[ii][0] = *(const short8*)(const void*)(_ap + pcq0); \
  dst[ii][1] = *(const short8*)(const void*)(_ap + pcq1); } }

#define G_RDB(dst, buf, qn) { _Pragma("unroll") for (int jj = 0; jj < 2; ++jj) { \
  const bf16* _bp = Bs + (buf)*8192 + (nw*64 + (qn)*32 + jj*16 + r16)*64; \
  dst[jj][0] = *(const short8*)(const void*)(_bp + pcq0); \
  dst[jj][1] = *(const short8*)(const void*)(_bp + pcq1); } }

#define G_MF(qm, qn, AF, BF) { _Pragma("unroll") for (int ii = 0; ii < 2; ++ii) \
  _Pragma("unroll") for (int jj = 0; jj < 2; ++jj) { \
    floatx4& _c = acc[(qm)*2 + ii][(qn)*2 + jj]; \
    _c = __builtin_amdgcn_mfma_f32_16x16x32_bf16(AF[ii][0], BF[jj][0], _c, 0, 0, 0); \
    _c = __builtin_amdgcn_mfma_f32_16x16x32_bf16(AF[ii][1], BF[jj][1], _c, 0, 0, 0); } }

__device__ __forceinline__ void mainloop_g(const bf16* __restrict__ A0g,
                                           const bf16* __restrict__ A1g,
                                           const bf16* __restrict__ Btg,
                                           bf16* As, bf16* Bs,
                                           int m0, int n0, floatx4 (&acc)[4][4]) {
  const int t = threadIdx.x, lane = t & 63, w = t >> 6;
  const int l3 = lane >> 3;
  const int gch8 = (((lane & 7) ^ l3) << 3);
  const int lnoff = lane << 3;
  const int mw = w & 3, nw = w >> 2;
  const int q = lane >> 4, r16 = lane & 15;
  const int pcq0 = ((q) ^ (r16 & 7)) << 3;
  const int pcq1 = ((4 + q) ^ (r16 & 7)) << 3;
  const int mwb = (mw & 1) * 128 + (mw >> 1) * 32;

  int a_sro[2][2], b_srg[2];
#pragma unroll
  for (int qm = 0; qm < 2; ++qm)
#pragma unroll
    for (int h = 0; h < 2; ++h)
      a_sro[qm][h] = (m0 + h*128 + qm*64 + w*8 + l3) * IN_SZ;
#pragma unroll
  for (int h = 0; h < 2; ++h)
    b_srg[h] = (n0 + h*64 + w*8 + l3) * KTOT;

  short8 afA[2][2], afB[2][2], bfrA[2][2], bfrB[2][2];

  // prologue: order A0q0, B0, A0q1, A1q0, B1, A1q1 (12 loads)
  ZR_SA(0,0,0); G_SB(0,0); ZR_SA(0,1,0);
  ZR_SA(1,0,1); G_SB(1,1); ZR_SA(1,1,1);
  WAIT_VM(8);               // A0q0 + B0 landed
  BAR();
  G_RDA(afA, 0, 0);
  G_RDB(bfrA, 0, 0);
  WAIT_LG(0);
  BAR();

#pragma unroll 1
  for (int it = 0; it < KTOT / 128; ++it) {
    const int tn0 = (2*it + 2 < KTOT/64) ? (2*it + 2) : (KTOT/64 - 1);
    const int tn1 = (2*it + 3 < KTOT/64) ? (2*it + 3) : (KTOT/64 - 1);
    // ph1
    G_RDB(bfrB,0,1); ZR_SA(0,0,tn0); BAR(); WAIT_LG(4); SCHED0; PRIO1; G_MF(0,0,afA,bfrA); PRIO0; WAIT_VM(8); BAR();
    // ph2 (no stage)
    G_RDA(afB,0,1);                  BAR(); WAIT_LG(4); SCHED0; PRIO1; G_MF(0,1,afA,bfrB); PRIO0; WAIT_VM(6); BAR();
    // ph3
    G_RDA(afA,1,0);  G_SB(0,tn0);    BAR(); WAIT_LG(4); SCHED0; PRIO1; G_MF(1,0,afB,bfrA); PRIO0; WAIT_VM(6); BAR();
    // ph4
    G_RDB(bfrA,1,0); ZR_SA(0,1,tn0); BAR(); WAIT_LG(4); SCHED0; PRIO1; G_MF(1,1,afB,bfrB); PRIO0; WAIT_VM(8); BAR();
    // ph5
    G_RDB(bfrB,1,1); ZR_SA(1,0,tn1); BAR(); WAIT_LG(4); SCHED0; PRIO1; G_MF(0,0,afA,bfrA); PRIO0; WAIT_VM(8); BAR();
    // ph6
    G_RDA(afB,1,1);  G_SB(1,tn1);    BAR(); WAIT_LG(4); SCHED0; PRIO1; G_MF(0,1,afA,bfrB); PRIO0; WAIT_VM(8); BAR();
    // ph7
    G_RDA(afA,0,0);  ZR_SA(1,1,tn1); BAR(); WAIT_LG(4); SCHED0; PRIO1; G_MF(1,0,afB,bfrA); PRIO0; WAIT_VM(8); BAR();
    // ph8 (no stage)
    G_RDB(bfrA,0,0);                 BAR(); WAIT_LG(4); SCHED0; PRIO1; G_MF(1,1,afB,bfrB); PRIO0; WAIT_VM(8); BAR();
  }
  asm volatile("s_waitcnt vmcnt(0)" ::: "memory");
  __syncthreads();
}

// ---------------- zr stage (256x256): sigmoid; z -> zbuf(bf16)+bits; r -> r*h
__global__ void __launch_bounds__(512, 1)
gemm_zr8(const bf16* __restrict__ xb, const bf16* __restrict__ hfp,
         const bf16* __restrict__ Bt, const float* __restrict__ bias,
         bf16* __restrict__ zbuf, bf16* __restrict__ rh,
         const int* __restrict__ slice_ptr, int use_slice,
         float* __restrict__ accp) {
  __shared__ __attribute__((aligned(16))) char smem[131072];
  bf16* As = (bf16*)smem;                 // [2][256*64]
  bf16* Bs = (bf16*)(smem + 65536);       // [2][256*64]
  const int m0 = blockIdx.y * 256;
  const int n0 = blockIdx.x * 256;
  floatx4 acc[8][4];
#pragma unroll
  for (int i = 0; i < 8; ++i)
#pragma unroll
    for (int j = 0; j < 4; ++j) acc[i][j] = (floatx4)0.0f;

  mainloop_zr(xb, hfp, Bt, As, Bs, m0, n0, acc);

  const int t = threadIdx.x;
  const int lane = t & 63, w = t >> 6;
  const int wm = w & 1, wn = w >> 1;
  const int q = lane >> 4, r16 = lane & 15;
  float* lds_f = (float*)smem;            // [128][256] f32 per half-pass
  const bool zmode = (n0 < GG);           // block-uniform (BN divides GG)
  const int nmin = use_slice ? *slice_ptr : 0;
  float bn[4];
#pragma unroll
  for (int j = 0; j < 4; ++j) bn[j] = bias[n0 + wn*64 + j*16 + r16];
  float lsum = 0.0f;

#pragma unroll
  for (int p = 0; p < 2; ++p) {           // two 128-row half-tiles (f32 = 128KB)
#pragma unroll
    for (int i4 = 0; i4 < 4; ++i4)
#pragma unroll
      for (int j = 0; j < 4; ++j) {
        const int n_loc = wn*64 + j*16 + r16;
        const int n = n0 + n_loc;
#pragma unroll
        for (int rr = 0; rr < 4; ++rr) {
          const int lr = wm*64 + i4*16 + q*4 + rr;
          float v = acc[p*4 + i4][j][rr] + bn[j];
          float s = 1.0f / (1.0f + __expf(-v));
          float ov;
          if (zmode) {
            float z = 0.875f * s + 0.125f;
            if (n >= nmin) lsum += -__log2f(z);
            ov = z;
          } else {
            ov = s;
          }
          lds_f[lr*256 + ((((n_loc >> 2) ^ (lr & 7)) << 2) | (n_loc & 3))] = ov;
        }
      }
    __syncthreads();
#pragma unroll
    for (int s2 = 0; s2 < 16; ++s2) {     // wave reads full rows -> 512B stores
      const int r = w*16 + s2;
      const int c = lane;
      floatx4 v4 = *(const floatx4*)&lds_f[r*256 + ((c ^ (r & 7)) << 2)];
      const int m = m0 + (r >> 6)*128 + p*64 + (r & 63);
      const int ncol = n0 + c*4;
      if (zmode) {
        bf16 o[4];
#pragma unroll
        for (int e = 0; e < 4; ++e) o[e] = __float2bfloat16(v4[e]);
        *(short4e*)&zbuf[(size_t)m * GG + ncol] = *(short4e*)o;
      } else {
        const int jc = ncol - GG;
        short4e hv = *(const short4e*)&hfp[(size_t)m * GG + jc];
        bf16 o[4];
#pragma unroll
        for (int e = 0; e < 4; ++e) {
          float hfv = __uint_as_float((unsigned)(unsigned short)hv[e] << 16);
          o[e] = __float2bfloat16(v4[e] * hfv);
        }
        *(short4e*)&rh[(size_t)m * GG + jc] = *(short4e*)o;
      }
    }
    __syncthreads();
  }
#pragma unroll
  for (int off = 32; off > 0; off >>= 1) lsum += __shfl_down(lsum, off, 64);
  float* sf = (float*)smem;
  if (lane == 0) sf[w] = lsum;
  __syncthreads();
  if (t == 0)
    atomicAdd(accp, sf[0]+sf[1]+sf[2]+sf[3]+sf[4]+sf[5]+sf[6]+sf[7]);
}

// ---------------- g stage (256x128): tanh + fixed-point update + outputs ----
__global__ void __launch_bounds__(512, 1)
gemm_g8(const bf16* __restrict__ xb, const bf16* __restrict__ rh,
        const bf16* __restrict__ Bt, const float* __restrict__ bias,
        const bf16* __restrict__ zbuf, const int* __restrict__ hidden,
        int col_off,
        float* __restrict__ out0, float* __restrict__ out1,
        bf16* __restrict__ hf_out, int write_hf,
        int write_bits, const float* __restrict__ accp,
        const int* __restrict__ slice_ptr, float* __restrict__ out2) {
  __shared__ __attribute__((aligned(16))) char smem[131072];
  bf16* As = (bf16*)smem;                 // [2][256*64]
  bf16* Bs = (bf16*)(smem + 65536);       // [2][128*64]
  const int m0 = blockIdx.y * 256;
  const int n0 = blockIdx.x * 128;
  floatx4 acc[4][4];
#pragma unroll
  for (int i = 0; i < 4; ++i)
#pragma unroll
    for (int j = 0; j < 4; ++j) acc[i][j] = (floatx4)0.0f;

  mainloop_g(xb, rh, Bt, As, Bs, m0, n0, acc);

  const int t = threadIdx.x;
  const int lane = t & 63, w = t >> 6;
  const int mw = w & 3, nw = w >> 2;
  const int q = lane >> 4, r16 = lane & 15;
  const int mwb = (mw & 1) * 128 + (mw >> 1) * 32;
  float* lds_f = (float*)smem;            // [256][128] f32 = 128KB, single pass
  float bn[4];
#pragma unroll
  for (int qn = 0; qn < 2; ++qn)
#pragma unroll
    for (int j = 0; j < 2; ++j) bn[qn*2 + j] = bias[n0 + nw*64 + qn*32 + j*16 + r16];

#pragma unroll
  for (int qm = 0; qm < 2; ++qm)
#pragma unroll
    for (int i = 0; i < 2; ++i)
#pragma unroll
      for (int qn = 0; qn < 2; ++qn)
#pragma unroll
        for (int j = 0; j < 2; ++j) {
          const int n_loc = nw*64 + qn*32 + j*16 + r16;
#pragma unroll
          for (int rr = 0; rr < 4; ++rr) {
            const int lr = mwb + qm*64 + i*16 + q*4 + rr;
            lds_f[lr*128 + ((((n_loc >> 2) ^ (lr & 7)) << 2) | (n_loc & 3))] =
                acc[qm*2 + i][qn*2 + j][rr] + bn[qn*2 + j];
          }
        }
  __syncthreads();
#pragma unroll
  for (int s2 = 0; s2 < 16; ++s2) {       // half-wave reads full rows
    const int r = w*2 + (lane >> 5) + s2*16;
    const int c = lane & 31;
    floatx4 v4 = *(const floatx4*)&lds_f[r*128 + ((c ^ (r & 7)) << 2)];
    const int m = m0 + r;
    const int ncol = n0 + c*4;
    short4e zb = *(const short4e*)&zbuf[(size_t)m * GG + ncol];
    int4 hd = *(const int4*)&hidden[(size_t)m * HSZ + col_off + ncol];
    const int hvv[4] = {hd.x, hd.y, hd.z, hd.w};
    floatx4 w0, w1;
    bf16 ob[4];
#pragma unroll
    for (int e = 0; e < 4; ++e) {
      float v = v4[e];
      float ex = __expf(2.0f * v);
      float gg = 1.0f - 2.0f / (ex + 1.0f);          // tanh(v)
      float z = __uint_as_float((unsigned)(unsigned short)zb[e] << 16);
      int zfix = (int)(z * 1024.0f);                 // trunc (z > 0)
      if (zfix < 1) zfix = 1;
      long long h = hvv[e];
      long long hupd = (h * (long long)zfix) >> 10;  // floor div 2^10
      float t2f = (1.0f - z) * gg * 8388608.0f;      // *2^23
      long long f2 = (long long)t2f;                 // trunc toward zero
      int hnew = (int)(hupd + f2);
      w0[e] = (float)hnew;
      w1[e] = (float)hnew * (1.0f / 8388608.0f);
      ob[e] = __float2bfloat16(w1[e]);
    }
    const size_t ob_ = (size_t)m * HSZ + col_off + ncol;
    *(floatx4*)&out0[ob_] = w0;
    *(floatx4*)&out1[ob_] = w1;
    if (write_hf) *(short4e*)&hf_out[(size_t)m * GG + ncol] = *(short4e*)ob;
  }
  if (write_bits && blockIdx.x == 0 && blockIdx.y == 0 && t == 0)
    *out2 = *accp + 32.0f * (float)(*slice_ptr) * (float)BATCH;
}

extern "C" void kernel_launch(void* const* d_in, const int* in_sizes, int n_in,
                              void* d_out, int out_size, void* d_ws, size_t ws_size,
                              hipStream_t stream) {
  const float* x      = (const float*)d_in[0];
  const int*   hidden = (const int*)d_in[1];
  const float* W_zr1  = (const float*)d_in[2];
  const float* b_zr1  = (const float*)d_in[3];
  const float* W_g1   = (const float*)d_in[4];
  const float* b_g1   = (const float*)d_in[5];
  const float* W_zr2  = (const float*)d_in[6];
  const float* b_zr2  = (const float*)d_in[7];
  const float* W_g2   = (const float*)d_in[8];
  const float* b_g2   = (const float*)d_in[9];
  const int*   slice  = (const int*)d_in[10];

  char* ws = (char*)d_ws;
  size_t off = 0;
  auto alloc = [&](size_t bytes) -> void* {
    void* p = ws + off;
    off += (bytes + 255) & ~(size_t)255;
    return p;
  };
  bf16* xb     = (bf16*)alloc((size_t)BATCH * IN_SZ * 2);
  bf16* wt_zr1 = (bf16*)alloc((size_t)2048 * 2048 * 2);
  bf16* wt_g1  = (bf16*)alloc((size_t)1024 * 2048 * 2);
  bf16* wt_zr2 = (bf16*)alloc((size_t)2048 * 2048 * 2);
  bf16* wt_g2  = (bf16*)alloc((size_t)1024 * 2048 * 2);
  bf16* hf     = (bf16*)alloc((size_t)BATCH * GG * 2);
  bf16* rh     = (bf16*)alloc((size_t)BATCH * GG * 2);
  bf16* zbuf   = (bf16*)alloc((size_t)BATCH * GG * 2);
  float* accp  = (float*)alloc(256);

  float* out0 = (float*)d_out;
  float* out1 = out0 + (size_t)BATCH * HSZ;
  float* out2 = out0 + 2 * (size_t)BATCH * HSZ;

  prep_all<<<3072 + 8192, 256, 0, stream>>>(x, xb, hidden, hf, accp,
                                            W_zr1, W_g1, W_zr2, W_g2,
                                            wt_zr1, wt_g1, wt_zr2, wt_g2);

  // stage 1: zr1 = sigmoid([x|h2f] @ W_zr1 + b)
  gemm_zr8<<<dim3(8, 32), 512, 0, stream>>>(xb, hf, wt_zr1, b_zr1, zbuf, rh, slice, 1, accp);
  // stage 2: g1 = tanh([x|r1*h2f] @ W_g1 + b); h1 update; writes h1_fl into hf
  gemm_g8<<<dim3(8, 32), 512, 0, stream>>>(xb, rh, wt_g1, b_g1, zbuf, hidden, 0,
                                           out0, out1, hf, 1, 0, accp, slice, out2);
  // stage 3: zr2 = sigmoid([x|h1f] @ W_zr2 + b)
  gemm_zr8<<<dim3(8, 32), 512, 0, stream>>>(xb, hf, wt_zr2, b_zr2, zbuf, rh, slice, 0, accp);
  // stage 4: g2 = tanh([x|r2*h1f] @ W_g2 + b); h2 update; writes optimal_bits
  gemm_g8<<<dim3(8, 32), 512, 0, stream>>>(xb, rh, wt_g2, b_g2, zbuf, hidden, 1024,
                                           out0, out1, hf, 0, 1, accp, slice, out2);
}

// Round 9
// 557.205 us; speedup vs baseline: 1.2170x; 1.2170x over previous
//
#include <hip/hip_runtime.h>
#include <hip/hip_bf16.h>

#define BATCH   8192
#define IN_SZ   1024
#define HSZ     2048
#define GG      1024
#define KTOT    2048

typedef __hip_bfloat16 bf16;
typedef __attribute__((ext_vector_type(8))) short  short8;
typedef __attribute__((ext_vector_type(4))) short  short4e;
typedef __attribute__((ext_vector_type(4))) float  floatx4;

typedef __attribute__((address_space(1))) const void gvoid_t;
typedef __attribute__((address_space(3))) void       lvoid_t;

__device__ __forceinline__ void async_ld16(void* lds, const void* g) {
  __builtin_amdgcn_global_load_lds((gvoid_t*)g, (lvoid_t*)lds, 16, 0, 0);
}

// ---------------- fused prep: x->bf16, h2->bf16 float, 4 weight transposes --
__global__ void prep_all(const float* __restrict__ x, bf16* __restrict__ xb,
                         const int* __restrict__ hidden, bf16* __restrict__ hf,
                         float* accp,
                         const float* __restrict__ W_zr1, const float* __restrict__ W_g1,
                         const float* __restrict__ W_zr2, const float* __restrict__ W_g2,
                         bf16* __restrict__ wt_zr1, bf16* __restrict__ wt_g1,
                         bf16* __restrict__ wt_zr2, bf16* __restrict__ wt_g2) {
  int b = blockIdx.x;
  int t = threadIdx.x;
  if (b < 3072) {
    const float* W; bf16* Wt; int N; int tb = b;
    if (tb < 1024)      { W = W_zr1; Wt = wt_zr1; N = 2048; }
    else if (tb < 1536) { W = W_g1;  Wt = wt_g1;  N = 1024; tb -= 1024; }
    else if (tb < 2560) { W = W_zr2; Wt = wt_zr2; N = 2048; tb -= 1536; }
    else                { W = W_g2;  Wt = wt_g2;  N = 1024; tb -= 2560; }
    int ntn = N >> 6;
    int k0 = (tb / ntn) * 64, n0 = (tb % ntn) * 64;
    __shared__ float tile[64][65];
    int kk = t >> 4, nn = (t & 15) * 4;
#pragma unroll
    for (int s = 0; s < 4; ++s) {
      int row = kk + s * 16;
      float4 v = *(const float4*)&W[(size_t)(k0 + row) * N + n0 + nn];
      tile[row][nn + 0] = v.x; tile[row][nn + 1] = v.y;
      tile[row][nn + 2] = v.z; tile[row][nn + 3] = v.w;
    }
    __syncthreads();
    int k8 = (t & 7) * 8;
#pragma unroll
    for (int s = 0; s < 2; ++s) {
      int nl = (t >> 3) + s * 32;
      bf16 vals[8];
#pragma unroll
      for (int u = 0; u < 8; ++u) vals[u] = __float2bfloat16(tile[k8 + u][nl]);
      *(short8*)&Wt[(size_t)(n0 + nl) * KTOT + k0 + k8] = *(short8*)vals;
    }
  } else {
    int idx = (b - 3072) * 256 + t;
    int i = idx * 4;
    float4 xv = *(const float4*)(x + i);
    xb[i + 0] = __float2bfloat16(xv.x);
    xb[i + 1] = __float2bfloat16(xv.y);
    xb[i + 2] = __float2bfloat16(xv.z);
    xb[i + 3] = __float2bfloat16(xv.w);
    int m = i >> 10, j = i & 1023;
    int4 hv = *(const int4*)(hidden + m * HSZ + GG + j);
    const float sc = 1.0f / 8388608.0f;   // 2^-23
    hf[i + 0] = __float2bfloat16((float)hv.x * sc);
    hf[i + 1] = __float2bfloat16((float)hv.y * sc);
    hf[i + 2] = __float2bfloat16((float)hv.z * sc);
    hf[i + 3] = __float2bfloat16((float)hv.w * sc);
    if (idx == 0) *accp = 0.0f;
  }
}

// =============================================================================
// v3: 4M x 2N wave grid so the fragment working set fits the 128-arch-VGPR
// half of the unified 256-reg/wave budget (acc -> 128/64 AGPRs; r3-r7 showed
// the v2 2Mx4N ping-pong set spilled and no launch-bounds form raises the cap
// — a 512-thread block always has 2 waves/EU, so arch+agpr <= 256 is the HW
// wall). qn-major phase order: (q0,n0)(q1,n0)(q0,n1)(q1,n1) per K-tile.
//   B: ONE 32-reg set, read in-phase at first use (ph1: n0, ph3: n1), reused
//      next phase. Read once per tile.
//   A: two 16-reg slots (af0=qm0, af1=qm1), single-buffered, refilled one
//      phase ahead of next use (slot is dead by then).
// Counted lgkmcnt: B-reads issued before A-prefetch -> in-order retirement
// makes LG(4)=B-done/A-pf-pending exact; LG(0) elsewhere drains prior pf.
// Stages placed AFTER the lgkm wait (all prior reads of the target region
// retired). Uniform vmcnt(8) [zr] / vmcnt(6) [g] = ~4 phases of loads in
// flight; every read of staged data is >=4 phases after its stage.
// =============================================================================

#define BAR()        asm volatile("s_barrier" ::: "memory")
#define WAIT_VM(n)   asm volatile("s_waitcnt vmcnt(" #n ")" ::: "memory")
#define WAIT_LG(n)   asm volatile("s_waitcnt lgkmcnt(" #n ")" ::: "memory")
#define SCHED0       __builtin_amdgcn_sched_barrier(0)
#define PRIO1        __builtin_amdgcn_s_setprio(1)
#define PRIO0        __builtin_amdgcn_s_setprio(0)

// ---- shared staging macros (64 rows x 64 k per call; chunk XOR pre-swizzled
//      on the global source, LDS dest linear) ----
#define SA1(buf, g, tk) { const int _kt = (tk) * 64; const bf16* _p; int _kl;  \
  if (_kt < IN_SZ) { _p = A0g; _kl = _kt; } else { _p = A1g; _kl = _kt - IN_SZ; } \
  async_ld16(As + (buf)*16384 + (g)*4096 + w*512 + lnoff,                      \
             _p + (m0 + (g)*64 + w*8 + l3) * IN_SZ + _kl + gch8); }

#define SB1z(buf, g, tk)                                                       \
  async_ld16(Bs + (buf)*16384 + (g)*4096 + w*512 + lnoff,                      \
             Btg + (n0 + (g)*64 + w*8 + l3) * KTOT + (tk)*64 + gch8);

#define SB1g(buf, g, tk)                                                       \
  async_ld16(Bs + (buf)*8192 + (g)*4096 + w*512 + lnoff,                       \
             Btg + (n0 + (g)*64 + w*8 + l3) * KTOT + (tk)*64 + gch8);

// ---- zr fragment ops: wave tile 64(M) x 128(N) ----
#define ZRA(dst, buf, qm) { _Pragma("unroll") for (int ii = 0; ii < 2; ++ii) { \
  const bf16* _ap = As + (buf)*16384 + (mw*64 + (qm)*32 + ii*16 + r16)*64;     \
  dst[ii][0] = *(const short8*)(const void*)(_ap + pcq0);                      \
  dst[ii][1] = *(const short8*)(const void*)(_ap + pcq1); } }

#define ZRB(buf, qn) { _Pragma("unroll") for (int jj = 0; jj < 4; ++jj) {      \
  const bf16* _bp = Bs + (buf)*16384 + (nw*128 + (qn)*64 + jj*16 + r16)*64;    \
  bfr[jj][0] = *(const short8*)(const void*)(_bp + pcq0);                      \
  bfr[jj][1] = *(const short8*)(const void*)(_bp + pcq1); } }

#define ZMF(qm, qn, AF) { _Pragma("unroll") for (int ii = 0; ii < 2; ++ii)     \
  _Pragma("unroll") for (int jj = 0; jj < 4; ++jj) {                           \
    floatx4& _c = acc[(qm)*2 + ii][(qn)*4 + jj];                               \
    _c = __builtin_amdgcn_mfma_f32_16x16x32_bf16(AF[ii][0], bfr[jj][0], _c, 0, 0, 0); \
    _c = __builtin_amdgcn_mfma_f32_16x16x32_bf16(AF[ii][1], bfr[jj][1], _c, 0, 0, 0); } }

__device__ __forceinline__ void mainloop_zr(const bf16* __restrict__ A0g,
                                            const bf16* __restrict__ A1g,
                                            const bf16* __restrict__ Btg,
                                            bf16* As, bf16* Bs,
                                            int m0, int n0, floatx4 (&acc)[4][8]) {
  const int t = threadIdx.x, lane = t & 63, w = t >> 6;
  const int l3 = lane >> 3;
  const int gch8 = (((lane & 7) ^ l3) << 3);
  const int lnoff = lane << 3;
  const int mw = w & 3, nw = w >> 2;
  const int q = lane >> 4, r16 = lane & 15;
  const int pcq0 = ((q) ^ (r16 & 7)) << 3;
  const int pcq1 = ((4 + q) ^ (r16 & 7)) << 3;

  short8 af0[2][2], af1[2][2], bfr[4][2];

  // prologue: buf0 <- t0 (A,B full), buf1 <- t1 (A full, B groups 0,2)
  SA1(0,0,0) SA1(0,1,0) SA1(0,2,0) SA1(0,3,0)
  SB1z(0,0,0) SB1z(0,1,0) SB1z(0,2,0) SB1z(0,3,0)
  SA1(1,0,1) SA1(1,1,1) SA1(1,2,1) SA1(1,3,1)
  SB1z(1,0,1) SB1z(1,2,1)
  WAIT_VM(6);                  // buf0 A+B landed (6 = buf1 stages in flight)
  BAR();
  ZRA(af0, 0, 0);
  WAIT_LG(0);
  BAR();

#pragma unroll 1
  for (int it = 0; it < KTOT / 128; ++it) {
    const int tO  = 2*it + 1;
    const int tn0 = (2*it + 2 < KTOT/64) ? (2*it + 2) : (KTOT/64 - 1);
    const int tn1 = (2*it + 3 < KTOT/64) ? (2*it + 3) : (KTOT/64 - 1);
    // ph1 (tE,q0,n0): B(n0,buf0) in-phase; prefetch af1(tE)
    ZRB(0,0); ZRA(af1,0,1);
    BAR(); WAIT_LG(4); SCHED0;
    SB1z(1,1,tO) SB1z(1,3,tO)
    PRIO1; ZMF(0,0,af0); PRIO0; WAIT_VM(8); BAR();
    // ph2 (tE,q1,n0)
    BAR(); WAIT_LG(0); SCHED0;
    SA1(0,0,tn0) SA1(0,1,tn0)
    PRIO1; ZMF(1,0,af1); PRIO0; WAIT_VM(8); BAR();
    // ph3 (tE,q0,n1): B(n1,buf0) in-phase
    ZRB(0,1);
    BAR(); WAIT_LG(0); SCHED0;
    SA1(0,2,tn0) SA1(0,3,tn0)
    PRIO1; ZMF(0,1,af0); PRIO0; WAIT_VM(8); BAR();
    // ph4 (tE,q1,n1): prefetch af0(tO)
    ZRA(af0,1,0);
    BAR(); WAIT_LG(4); SCHED0;
    SB1z(0,0,tn0) SB1z(0,2,tn0)
    PRIO1; ZMF(1,1,af1); PRIO0; WAIT_VM(8); BAR();
    // ph5 (tO,q0,n0): B(n0,buf1); prefetch af1(tO)
    ZRB(1,0); ZRA(af1,1,1);
    BAR(); WAIT_LG(4); SCHED0;
    SB1z(0,1,tn0) SB1z(0,3,tn0)
    PRIO1; ZMF(0,0,af0); PRIO0; WAIT_VM(8); BAR();
    // ph6 (tO,q1,n0)
    BAR(); WAIT_LG(0); SCHED0;
    SA1(1,0,tn1) SA1(1,1,tn1)
    PRIO1; ZMF(1,0,af1); PRIO0; WAIT_VM(8); BAR();
    // ph7 (tO,q0,n1): B(n1,buf1)
    ZRB(1,1);
    BAR(); WAIT_LG(0); SCHED0;
    SA1(1,2,tn1) SA1(1,3,tn1)
    PRIO1; ZMF(0,1,af0); PRIO0; WAIT_VM(8); BAR();
    // ph8 (tO,q1,n1): prefetch af0(tE')
    ZRA(af0,0,0);
    BAR(); WAIT_LG(4); SCHED0;
    SB1z(1,0,tn1) SB1z(1,2,tn1)
    PRIO1; ZMF(1,1,af1); PRIO0; WAIT_VM(8); BAR();
  }
  asm volatile("s_waitcnt vmcnt(0)" ::: "memory");
  __syncthreads();
}

// ---- g fragment ops: wave tile 64(M) x 64(N) ----
#define GRB(buf, qn) { _Pragma("unroll") for (int jj = 0; jj < 2; ++jj) {      \
  const bf16* _bp = Bs + (buf)*8192 + (nw*64 + (qn)*32 + jj*16 + r16)*64;      \
  bfr[jj][0] = *(const short8*)(const void*)(_bp + pcq0);                      \
  bfr[jj][1] = *(const short8*)(const void*)(_bp + pcq1); } }

#define GMF(qm, qn, AF) { _Pragma("unroll") for (int ii = 0; ii < 2; ++ii)     \
  _Pragma("unroll") for (int jj = 0; jj < 2; ++jj) {                           \
    floatx4& _c = acc[(qm)*2 + ii][(qn)*2 + jj];                               \
    _c = __builtin_amdgcn_mfma_f32_16x16x32_bf16(AF[ii][0], bfr[jj][0], _c, 0, 0, 0); \
    _c = __builtin_amdgcn_mfma_f32_16x16x32_bf16(AF[ii][1], bfr[jj][1], _c, 0, 0, 0); } }

__device__ __forceinline__ void mainloop_g(const bf16* __restrict__ A0g,
                                           const bf16* __restrict__ A1g,
                                           const bf16* __restrict__ Btg,
                                           bf16* As, bf16* Bs,
                                           int m0, int n0, floatx4 (&acc)[4][4]) {
  const int t = threadIdx.x, lane = t & 63, w = t >> 6;
  const int l3 = lane >> 3;
  const int gch8 = (((lane & 7) ^ l3) << 3);
  const int lnoff = lane << 3;
  const int mw = w & 3, nw = w >> 2;
  const int q = lane >> 4, r16 = lane & 15;
  const int pcq0 = ((q) ^ (r16 & 7)) << 3;
  const int pcq1 = ((4 + q) ^ (r16 & 7)) << 3;

  short8 af0[2][2], af1[2][2], bfr[2][2];

  // prologue: buf0 <- t0, buf1 <- t1 (A 4 groups + B 2 groups each)
  SA1(0,0,0) SA1(0,1,0) SA1(0,2,0) SA1(0,3,0)
  SB1g(0,0,0) SB1g(0,1,0)
  SA1(1,0,1) SA1(1,1,1) SA1(1,2,1) SA1(1,3,1)
  SB1g(1,0,1) SB1g(1,1,1)
  WAIT_VM(6);
  BAR();
  ZRA(af0, 0, 0);
  WAIT_LG(0);
  BAR();

#pragma unroll 1
  for (int it = 0; it < KTOT / 128; ++it) {
    const int tn0 = (2*it + 2 < KTOT/64) ? (2*it + 2) : (KTOT/64 - 1);
    const int tn1 = (2*it + 3 < KTOT/64) ? (2*it + 3) : (KTOT/64 - 1);
    // ph1 (tE,q0,n0)
    GRB(0,0); ZRA(af1,0,1);
    BAR(); WAIT_LG(4); SCHED0;
    PRIO1; GMF(0,0,af0); PRIO0; WAIT_VM(6); BAR();
    // ph2 (tE,q1,n0)
    BAR(); WAIT_LG(0); SCHED0;
    SA1(0,0,tn0) SA1(0,1,tn0)
    PRIO1; GMF(1,0,af1); PRIO0; WAIT_VM(6); BAR();
    // ph3 (tE,q0,n1)
    GRB(0,1);
    BAR(); WAIT_LG(0); SCHED0;
    SA1(0,2,tn0) SA1(0,3,tn0)
    PRIO1; GMF(0,1,af0); PRIO0; WAIT_VM(6); BAR();
    // ph4 (tE,q1,n1): prefetch af0(tO)
    ZRA(af0,1,0);
    BAR(); WAIT_LG(4); SCHED0;
    SB1g(0,0,tn0) SB1g(0,1,tn0)
    PRIO1; GMF(1,1,af1); PRIO0; WAIT_VM(6); BAR();
    // ph5 (tO,q0,n0): prefetch af1(tO)
    GRB(1,0); ZRA(af1,1,1);
    BAR(); WAIT_LG(4); SCHED0;
    PRIO1; GMF(0,0,af0); PRIO0; WAIT_VM(6); BAR();
    // ph6 (tO,q1,n0)
    BAR(); WAIT_LG(0); SCHED0;
    SA1(1,0,tn1) SA1(1,1,tn1)
    PRIO1; GMF(1,0,af1); PRIO0; WAIT_VM(6); BAR();
    // ph7 (tO,q0,n1)
    GRB(1,1);
    BAR(); WAIT_LG(0); SCHED0;
    SA1(1,2,tn1) SA1(1,3,tn1)
    PRIO1; GMF(0,1,af0); PRIO0; WAIT_VM(6); BAR();
    // ph8 (tO,q1,n1): prefetch af0(tE')
    ZRA(af0,0,0);
    BAR(); WAIT_LG(4); SCHED0;
    SB1g(1,0,tn1) SB1g(1,1,tn1)
    PRIO1; GMF(1,1,af1); PRIO0; WAIT_VM(6); BAR();
  }
  asm volatile("s_waitcnt vmcnt(0)" ::: "memory");
  __syncthreads();
}

// ---------------- zr stage (256x256): sigmoid; z -> zbuf(bf16)+bits; r -> r*h
__global__ void __launch_bounds__(512, 1)
gemm_zr8(const bf16* __restrict__ xb, const bf16* __restrict__ hfp,
         const bf16* __restrict__ Bt, const float* __restrict__ bias,
         bf16* __restrict__ zbuf, bf16* __restrict__ rh,
         const int* __restrict__ slice_ptr, int use_slice,
         float* __restrict__ accp) {
  __shared__ __attribute__((aligned(16))) char smem[131072];
  bf16* As = (bf16*)smem;                 // [2][256*64]
  bf16* Bs = (bf16*)(smem + 65536);       // [2][256*64]
  const int m0 = blockIdx.y * 256;
  const int n0 = blockIdx.x * 256;
  floatx4 acc[4][8];
#pragma unroll
  for (int i = 0; i < 4; ++i)
#pragma unroll
    for (int j = 0; j < 8; ++j) acc[i][j] = (floatx4)0.0f;

  mainloop_zr(xb, hfp, Bt, As, Bs, m0, n0, acc);

  const int t = threadIdx.x;
  const int lane = t & 63, w = t >> 6;
  const int mw = w & 3, nw = w >> 2;
  const int q = lane >> 4, r16 = lane & 15;
  float* lds_f = (float*)smem;            // [128][256] f32 per half-pass
  const bool zmode = (n0 < GG);           // block-uniform (BN divides GG)
  const int nmin = use_slice ? *slice_ptr : 0;
  float bn[8];
#pragma unroll
  for (int jn = 0; jn < 8; ++jn) bn[jn] = bias[n0 + nw*128 + jn*16 + r16];
  float lsum = 0.0f;

#pragma unroll
  for (int p = 0; p < 2; ++p) {           // rows [p*128, p*128+128)
    if ((mw >> 1) == p) {                 // wave-uniform: half the waves write
#pragma unroll
      for (int i = 0; i < 4; ++i)
#pragma unroll
        for (int jn = 0; jn < 8; ++jn) {
          const int n_loc = nw*128 + jn*16 + r16;
          const int n = n0 + n_loc;
#pragma unroll
          for (int rr = 0; rr < 4; ++rr) {
            const int lr = (mw & 1)*64 + i*16 + q*4 + rr;
            float v = acc[i][jn][rr] + bn[jn];
            float s = 1.0f / (1.0f + __expf(-v));
            float ov;
            if (zmode) {
              float z = 0.875f * s + 0.125f;
              if (n >= nmin) lsum += -__log2f(z);
              ov = z;
            } else {
              ov = s;
            }
            lds_f[lr*256 + ((((n_loc >> 2) ^ (lr & 7)) << 2) | (n_loc & 3))] = ov;
          }
        }
    }
    __syncthreads();
#pragma unroll
    for (int s2 = 0; s2 < 16; ++s2) {     // all waves: full rows -> 8B stores
      const int r = w*16 + s2;
      const int c = lane;
      floatx4 v4 = *(const floatx4*)&lds_f[r*256 + ((c ^ (r & 7)) << 2)];
      const int m = m0 + p*128 + r;
      const int ncol = n0 + c*4;
      if (zmode) {
        bf16 o[4];
#pragma unroll
        for (int e = 0; e < 4; ++e) o[e] = __float2bfloat16(v4[e]);
        *(short4e*)&zbuf[(size_t)m * GG + ncol] = *(short4e*)o;
      } else {
        const int jc = ncol - GG;
        short4e hv = *(const short4e*)&hfp[(size_t)m * GG + jc];
        bf16 o[4];
#pragma unroll
        for (int e = 0; e < 4; ++e) {
          float hfv = __uint_as_float((unsigned)(unsigned short)hv[e] << 16);
          o[e] = __float2bfloat16(v4[e] * hfv);
        }
        *(short4e*)&rh[(size_t)m * GG + jc] = *(short4e*)o;
      }
    }
    __syncthreads();
  }
#pragma unroll
  for (int off = 32; off > 0; off >>= 1) lsum += __shfl_down(lsum, off, 64);
  float* sf = (float*)smem;
  if (lane == 0) sf[w] = lsum;
  __syncthreads();
  if (t == 0)
    atomicAdd(accp, sf[0]+sf[1]+sf[2]+sf[3]+sf[4]+sf[5]+sf[6]+sf[7]);
}

// ---------------- g stage (256x128): tanh + fixed-point update + outputs ----
__global__ void __launch_bounds__(512, 1)
gemm_g8(const bf16* __restrict__ xb, const bf16* __restrict__ rh,
        const bf16* __restrict__ Bt, const float* __restrict__ bias,
        const bf16* __restrict__ zbuf, const int* __restrict__ hidden,
        int col_off,
        float* __restrict__ out0, float* __restrict__ out1,
        bf16* __restrict__ hf_out, int write_hf,
        int write_bits, const float* __restrict__ accp,
        const int* __restrict__ slice_ptr, float* __restrict__ out2) {
  __shared__ __attribute__((aligned(16))) char smem[131072];
  bf16* As = (bf16*)smem;                 // [2][256*64]
  bf16* Bs = (bf16*)(smem + 65536);       // [2][128*64]
  const int m0 = blockIdx.y * 256;
  const int n0 = blockIdx.x * 128;
  floatx4 acc[4][4];
#pragma unroll
  for (int i = 0; i < 4; ++i)
#pragma unroll
    for (int j = 0; j < 4; ++j) acc[i][j] = (floatx4)0.0f;

  mainloop_g(xb, rh, Bt, As, Bs, m0, n0, acc);

  const int t = threadIdx.x;
  const int lane = t & 63, w = t >> 6;
  const int mw = w & 3, nw = w >> 2;
  const int q = lane >> 4, r16 = lane & 15;
  float* lds_f = (float*)smem;            // [256][128] f32 = 128KB, single pass
  float bn[4];
#pragma unroll
  for (int jj = 0; jj < 4; ++jj) bn[jj] = bias[n0 + nw*64 + jj*16 + r16];

#pragma unroll
  for (int i = 0; i < 4; ++i)
#pragma unroll
    for (int jj = 0; jj < 4; ++jj) {
      const int n_loc = nw*64 + jj*16 + r16;
#pragma unroll
      for (int rr = 0; rr < 4; ++rr) {
        const int lr = mw*64 + i*16 + q*4 + rr;
        lds_f[lr*128 + ((((n_loc >> 2) ^ (lr & 7)) << 2) | (n_loc & 3))] =
            acc[i][jj][rr] + bn[jj];
      }
    }
  __syncthreads();
#pragma unroll
  for (int s2 = 0; s2 < 16; ++s2) {       // half-wave reads full rows
    const int r = w*2 + (lane >> 5) + s2*16;
    const int c = lane & 31;
    floatx4 v4 = *(const floatx4*)&lds_f[r*128 + ((c ^ (r & 7)) << 2)];
    const int m = m0 + r;
    const int ncol = n0 + c*4;
    short4e zb = *(const short4e*)&zbuf[(size_t)m * GG + ncol];
    int4 hd = *(const int4*)&hidden[(size_t)m * HSZ + col_off + ncol];
    const int hvv[4] = {hd.x, hd.y, hd.z, hd.w};
    floatx4 w0, w1;
    bf16 ob[4];
#pragma unroll
    for (int e = 0; e < 4; ++e) {
      float v = v4[e];
      float ex = __expf(2.0f * v);
      float gg = 1.0f - 2.0f / (ex + 1.0f);          // tanh(v)
      float z = __uint_as_float((unsigned)(unsigned short)zb[e] << 16);
      int zfix = (int)(z * 1024.0f);                 // trunc (z > 0)
      if (zfix < 1) zfix = 1;
      long long h = hvv[e];
      long long hupd = (h * (long long)zfix) >> 10;  // floor div 2^10
      float t2f = (1.0f - z) * gg * 8388608.0f;      // *2^23
      long long f2 = (long long)t2f;                 // trunc toward zero
      int hnew = (int)(hupd + f2);
      w0[e] = (float)hnew;
      w1[e] = (float)hnew * (1.0f / 8388608.0f);
      ob[e] = __float2bfloat16(w1[e]);
    }
    const size_t ob_ = (size_t)m * HSZ + col_off + ncol;
    *(floatx4*)&out0[ob_] = w0;
    *(floatx4*)&out1[ob_] = w1;
    if (write_hf) *(short4e*)&hf_out[(size_t)m * GG + ncol] = *(short4e*)ob;
  }
  if (write_bits && blockIdx.x == 0 && blockIdx.y == 0 && t == 0)
    *out2 = *accp + 32.0f * (float)(*slice_ptr) * (float)BATCH;
}

extern "C" void kernel_launch(void* const* d_in, const int* in_sizes, int n_in,
                              void* d_out, int out_size, void* d_ws, size_t ws_size,
                              hipStream_t stream) {
  const float* x      = (const float*)d_in[0];
  const int*   hidden = (const int*)d_in[1];
  const float* W_zr1  = (const float*)d_in[2];
  const float* b_zr1  = (const float*)d_in[3];
  const float* W_g1   = (const float*)d_in[4];
  const float* b_g1   = (const float*)d_in[5];
  const float* W_zr2  = (const float*)d_in[6];
  const float* b_zr2  = (const float*)d_in[7];
  const float* W_g2   = (const float*)d_in[8];
  const float* b_g2   = (const float*)d_in[9];
  const int*   slice  = (const int*)d_in[10];

  char* ws = (char*)d_ws;
  size_t off = 0;
  auto alloc = [&](size_t bytes) -> void* {
    void* p = ws + off;
    off += (bytes + 255) & ~(size_t)255;
    return p;
  };
  bf16* xb     = (bf16*)alloc((size_t)BATCH * IN_SZ * 2);
  bf16* wt_zr1 = (bf16*)alloc((size_t)2048 * 2048 * 2);
  bf16* wt_g1  = (bf16*)alloc((size_t)1024 * 2048 * 2);
  bf16* wt_zr2 = (bf16*)alloc((size_t)2048 * 2048 * 2);
  bf16* wt_g2  = (bf16*)alloc((size_t)1024 * 2048 * 2);
  bf16* hf     = (bf16*)alloc((size_t)BATCH * GG * 2);
  bf16* rh     = (bf16*)alloc((size_t)BATCH * GG * 2);
  bf16* zbuf   = (bf16*)alloc((size_t)BATCH * GG * 2);
  float* accp  = (float*)alloc(256);

  float* out0 = (float*)d_out;
  float* out1 = out0 + (size_t)BATCH * HSZ;
  float* out2 = out0 + 2 * (size_t)BATCH * HSZ;

  prep_all<<<3072 + 8192, 256, 0, stream>>>(x, xb, hidden, hf, accp,
                                            W_zr1, W_g1, W_zr2, W_g2,
                                            wt_zr1, wt_g1, wt_zr2, wt_g2);

  // stage 1: zr1 = sigmoid([x|h2f] @ W_zr1 + b)
  gemm_zr8<<<dim3(8, 32), 512, 0, stream>>>(xb, hf, wt_zr1, b_zr1, zbuf, rh, slice, 1, accp);
  // stage 2: g1 = tanh([x|r1*h2f] @ W_g1 + b); h1 update; writes h1_fl into hf
  gemm_g8<<<dim3(8, 32), 512, 0, stream>>>(xb, rh, wt_g1, b_g1, zbuf, hidden, 0,
                                           out0, out1, hf, 1, 0, accp, slice, out2);
  // stage 3: zr2 = sigmoid([x|h1f] @ W_zr2 + b)
  gemm_zr8<<<dim3(8, 32), 512, 0, stream>>>(xb, hf, wt_zr2, b_zr2, zbuf, rh, slice, 0, accp);
  // stage 4: g2 = tanh([x|r2*h1f] @ W_g2 + b); h2 update; writes optimal_bits
  gemm_g8<<<dim3(8, 32), 512, 0, stream>>>(xb, rh, wt_g2, b_g2, zbuf, hidden, 1024,
                                           out0, out1, hf, 0, 1, accp, slice, out2);
}